// Round 1
// baseline (381.016 us; speedup 1.0000x reference)
//
#include <hip/hip_runtime.h>

// Fused cross-attention: out = concat(dec, softmax_e(enc·dec^T)^T-weighted enc)
// B=8, T_enc=T_dec=2048, D=512, fp32 in/out.
// Flash-style: per block = (batch, 32 decoder rows), loop encoder in chunks of 32.
// QK^T in split-fp16 (S = Khi*(Qhi+Qlo), fp32 MFMA accum) for accuracy.

typedef _Float16 f16;
typedef f16 f16x8 __attribute__((ext_vector_type(8)));
typedef f16 f16x4 __attribute__((ext_vector_type(4)));
typedef float f32x4 __attribute__((ext_vector_type(4)));

#define NB 8
#define TE 2048
#define TD 2048
#define DD 512
#define TBLK 32
#define EBLK 32
#define NCH (TE / EBLK)

// LDS layout (bytes)
#define OQHI 0          // [32][512] f16, 1024B rows, XOR-swizzled
#define OQLO 32768      // [32][512] f16
#define OKHI 65536      // [32][512] f16
#define OKT  98304      // [512][40] f16, 80B rows (transposed V for PV A-operand)
#define OS   139264     // [4][32][34] f32 partial S
#define OP   156672     // [32][40] f16 P[t][e]
#define OAL  159232     // [32] f32 alpha
#define OLL  159360     // [32] f32 l
#define SMEM_BYTES 159488

__device__ __forceinline__ int swz1k(int row, int byteInRow) {
    return row * 1024 + (byteInRow ^ ((row & 7) << 4));
}

__global__ __launch_bounds__(512)
void attn_fused(const float* __restrict__ enc, const float* __restrict__ dec,
                float* __restrict__ out) {
    __shared__ __align__(16) char sm[SMEM_BYTES];
    const int tid  = threadIdx.x;
    const int b    = blockIdx.x & 7;          // XCD-pinned batch
    const int t0   = (blockIdx.x >> 3) * TBLK;
    const int lane = tid & 63;
    const int wv   = tid >> 6;                // wave id 0..7
    const int li   = lane & 15;
    const int gi   = lane >> 4;

    const float* encB = enc + (size_t)b * TE * DD;
    const float* decB = dec + (size_t)b * TD * DD;
    float*       outB = out + (size_t)b * TD * (2 * DD);

    // ---- Q stage (fp16 hi/lo) + dec passthrough to out[:, 0:512] ----
    for (int i = tid; i < TBLK * (DD / 4); i += 512) {
        int t  = i >> 7;     // 128 float4 per row
        int c4 = i & 127;
        float4 q = ((const float4*)(decB + (size_t)(t0 + t) * DD))[c4];
        ((float4*)(outB + (size_t)(t0 + t) * (2 * DD)))[c4] = q;
        f16 h0 = (f16)q.x, h1 = (f16)q.y, h2 = (f16)q.z, h3 = (f16)q.w;
        f16 l0 = (f16)(q.x - (float)h0), l1 = (f16)(q.y - (float)h1);
        f16 l2 = (f16)(q.z - (float)h2), l3 = (f16)(q.w - (float)h3);
        f16x4 hv = {h0, h1, h2, h3};
        f16x4 lv = {l0, l1, l2, l3};
        int off = swz1k(t, 8 * c4);
        *(f16x4*)(sm + OQHI + off) = hv;
        *(f16x4*)(sm + OQLO + off) = lv;
    }

    // softmax ownership: wave wv owns columns t = 4*wv + c, c = lane&3; er = lane>>2
    const int c    = lane & 3;
    const int er   = lane >> 2;
    const int tcol = 4 * wv + c;
    float mrun = -3.0e38f, lrun = 0.0f;
    const float L2E = 1.44269504088896f;

    // ctx^T accumulators: wave owns d in [64*wv, 64*wv+64): 4 d-tiles x 2 t-tiles
    f32x4 ctx[4][2];
    #pragma unroll
    for (int md = 0; md < 4; ++md) {
        ctx[md][0] = (f32x4){0.f, 0.f, 0.f, 0.f};
        ctx[md][1] = (f32x4){0.f, 0.f, 0.f, 0.f};
    }

    for (int ch = 0; ch < NCH; ++ch) {
        const int e0 = ch * EBLK;
        __syncthreads();                              // B0: prev PV done
        // ---- stage K chunk: Khi row-major (swizzled) + Kt transposed ----
        {
            const int d = tid;
            float va[16], vb[16];
            #pragma unroll
            for (int p = 0; p < 16; ++p) {
                va[p] = encB[(size_t)(e0 + 2 * p) * DD + d];
                vb[p] = encB[(size_t)(e0 + 2 * p + 1) * DD + d];
            }
            #pragma unroll
            for (int p = 0; p < 16; ++p) {
                f16 ha = (f16)va[p], hb = (f16)vb[p];
                union { f16 h[2]; unsigned u; } pk;
                pk.h[0] = ha; pk.h[1] = hb;
                *(unsigned*)(sm + OKT + d * 80 + 4 * p) = pk.u;
                *(f16*)(sm + OKHI + swz1k(2 * p,     2 * d)) = ha;
                *(f16*)(sm + OKHI + swz1k(2 * p + 1, 2 * d)) = hb;
            }
        }
        __syncthreads();                              // B1
        // ---- QK^T partial: wave = k-slice [64*wv, 64*wv+64) over full 32x32 S ----
        f32x4 sacc[2][2];
        #pragma unroll
        for (int et = 0; et < 2; ++et) {
            sacc[et][0] = (f32x4){0.f, 0.f, 0.f, 0.f};
            sacc[et][1] = (f32x4){0.f, 0.f, 0.f, 0.f};
        }
        #pragma unroll
        for (int kk = 0; kk < 2; ++kk) {
            int d0 = 64 * wv + 32 * kk;
            int cb = 2 * d0 + 16 * gi;
            f16x8 aF[2], bH[2], bL[2];
            #pragma unroll
            for (int et = 0; et < 2; ++et)
                aF[et] = *(const f16x8*)(sm + OKHI + swz1k(16 * et + li, cb));
            #pragma unroll
            for (int tt = 0; tt < 2; ++tt) {
                bH[tt] = *(const f16x8*)(sm + OQHI + swz1k(16 * tt + li, cb));
                bL[tt] = *(const f16x8*)(sm + OQLO + swz1k(16 * tt + li, cb));
            }
            #pragma unroll
            for (int et = 0; et < 2; ++et)
                #pragma unroll
                for (int tt = 0; tt < 2; ++tt) {
                    sacc[et][tt] = __builtin_amdgcn_mfma_f32_16x16x32_f16(aF[et], bH[tt], sacc[et][tt], 0, 0, 0);
                    sacc[et][tt] = __builtin_amdgcn_mfma_f32_16x16x32_f16(aF[et], bL[tt], sacc[et][tt], 0, 0, 0);
                }
        }
        if (wv < 4) {
            #pragma unroll
            for (int et = 0; et < 2; ++et)
                #pragma unroll
                for (int tt = 0; tt < 2; ++tt)
                    #pragma unroll
                    for (int r = 0; r < 4; ++r) {
                        int erow = 16 * et + 4 * gi + r;
                        int tc   = 16 * tt + li;
                        *(float*)(sm + OS + wv * 4352 + erow * 136 + tc * 4) = sacc[et][tt][r];
                    }
        }
        __syncthreads();                              // B2
        if (wv >= 4) {
            #pragma unroll
            for (int et = 0; et < 2; ++et)
                #pragma unroll
                for (int tt = 0; tt < 2; ++tt)
                    #pragma unroll
                    for (int r = 0; r < 4; ++r) {
                        int erow = 16 * et + 4 * gi + r;
                        int tc   = 16 * tt + li;
                        float* p = (float*)(sm + OS + (wv - 4) * 4352 + erow * 136 + tc * 4);
                        *p += sacc[et][tt][r];
                    }
        }
        __syncthreads();                              // B3
        // ---- online softmax (owner waves; all lanes active) ----
        {
            float s1 = 0.f, s2 = 0.f;
            #pragma unroll
            for (int bu = 0; bu < 4; ++bu) {
                s1 += *(const float*)(sm + OS + bu * 4352 + er * 136 + tcol * 4);
                s2 += *(const float*)(sm + OS + bu * 4352 + (er + 16) * 136 + tcol * 4);
            }
            float v = fmaxf(s1, s2);
            v = fmaxf(v, __shfl_xor(v, 4));
            v = fmaxf(v, __shfl_xor(v, 8));
            v = fmaxf(v, __shfl_xor(v, 16));
            v = fmaxf(v, __shfl_xor(v, 32));
            float mnew  = fmaxf(mrun, v);
            float alpha = exp2f((mrun - mnew) * L2E);
            float p1 = exp2f((s1 - mnew) * L2E);
            float p2 = exp2f((s2 - mnew) * L2E);
            float ps = p1 + p2;
            ps += __shfl_xor(ps, 4);
            ps += __shfl_xor(ps, 8);
            ps += __shfl_xor(ps, 16);
            ps += __shfl_xor(ps, 32);
            lrun = lrun * alpha + ps;
            mrun = mnew;
            *(f16*)(sm + OP + tcol * 80 + 2 * er)        = (f16)p1;
            *(f16*)(sm + OP + tcol * 80 + 2 * (er + 16)) = (f16)p2;
            if (er == 0) *(float*)(sm + OAL + 4 * tcol) = alpha;
        }
        __syncthreads();                              // B4
        // ---- PV: ctx^T[d][t] += sum_e Kt[d][e] * P[t][e] ----
        {
            float a0 = *(const float*)(sm + OAL + 4 * li);
            float a1 = *(const float*)(sm + OAL + 4 * (16 + li));
            f16x8 bP0 = *(const f16x8*)(sm + OP + li * 80 + 16 * gi);
            f16x8 bP1 = *(const f16x8*)(sm + OP + (16 + li) * 80 + 16 * gi);
            #pragma unroll
            for (int md = 0; md < 4; ++md) {
                f16x8 aV = *(const f16x8*)(sm + OKT + (64 * wv + 16 * md + li) * 80 + 16 * gi);
                #pragma unroll
                for (int r = 0; r < 4; ++r) { ctx[md][0][r] *= a0; ctx[md][1][r] *= a1; }
                ctx[md][0] = __builtin_amdgcn_mfma_f32_16x16x32_f16(aV, bP0, ctx[md][0], 0, 0, 0);
                ctx[md][1] = __builtin_amdgcn_mfma_f32_16x16x32_f16(aV, bP1, ctx[md][1], 0, 0, 0);
            }
        }
    }

    // ---- epilogue: divide by l, write context half ----
    if (er == 0) *(float*)(sm + OLL + 4 * tcol) = lrun;
    __syncthreads();
    float inv0 = 1.0f / *(const float*)(sm + OLL + 4 * li);
    float inv1 = 1.0f / *(const float*)(sm + OLL + 4 * (16 + li));
    #pragma unroll
    for (int md = 0; md < 4; ++md) {
        #pragma unroll
        for (int tt = 0; tt < 2; ++tt) {
            float inv = tt ? inv1 : inv0;
            int t = t0 + 16 * tt + li;
            int d = 64 * wv + 16 * md + 4 * gi;
            float4 o;
            o.x = ctx[md][tt][0] * inv;
            o.y = ctx[md][tt][1] * inv;
            o.z = ctx[md][tt][2] * inv;
            o.w = ctx[md][tt][3] * inv;
            *(float4*)(outB + (size_t)t * (2 * DD) + DD + d) = o;
        }
    }
}

extern "C" void kernel_launch(void* const* d_in, const int* in_sizes, int n_in,
                              void* d_out, int out_size, void* d_ws, size_t ws_size,
                              hipStream_t stream) {
    const float* enc = (const float*)d_in[0];
    const float* dec = (const float*)d_in[1];
    float* out = (float*)d_out;
    dim3 grid(NB * (TD / TBLK));   // 512 blocks: b = bid&7 (XCD pin), ttile = bid>>3
    dim3 block(512);
    attn_fused<<<grid, block, 0, stream>>>(enc, dec, out);
}

// Round 2
// 303.884 us; speedup vs baseline: 1.2538x; 1.2538x over previous
//
#include <hip/hip_runtime.h>

// Fused cross-attention: out = concat(dec, softmax_e(enc·dec^T)^T-weighted enc)
// B=8, T_enc=T_dec=2048, D=512, fp32 in/out.
// Flash-style: per block = (batch, 32 decoder rows), loop encoder in chunks of 32.
// QK^T in split-fp16 (S = Khi*(Qhi+Qlo), fp32 MFMA accum) for accuracy.
// R2: T14 prefetch staging (loads for ch+1 issued before ch's compute),
//     wide b64 staging writes, KT sigma-swizzle (write+read) for bank spread.

typedef _Float16 f16;
typedef f16 f16x8 __attribute__((ext_vector_type(8)));
typedef f16 f16x4 __attribute__((ext_vector_type(4)));
typedef float f32x4 __attribute__((ext_vector_type(4)));

#define NB 8
#define TE 2048
#define TD 2048
#define DD 512
#define TBLK 32
#define EBLK 32
#define NCH (TE / EBLK)

// LDS layout (bytes)
#define OQHI 0          // [32][512] f16, 1024B rows, XOR-swizzled
#define OQLO 32768      // [32][512] f16
#define OKHI 65536      // [32][512] f16
#define OKT  98304      // [512][40] f16, 80B rows, sigma-swizzled e-offset
#define OS   139264     // [4][32][34] f32 partial S
#define OP   156672     // [32][40] f16 P[t][e]
#define OAL  159232     // [32] f32 alpha
#define OLL  159360     // [32] f32 l
#define SMEM_BYTES 159488

__device__ __forceinline__ int swz1k(int row, int byteInRow) {
    return row * 1024 + (byteInRow ^ ((row & 7) << 4));
}

__global__ __launch_bounds__(512)
void attn_fused(const float* __restrict__ enc, const float* __restrict__ dec,
                float* __restrict__ out) {
    __shared__ __align__(16) char sm[SMEM_BYTES];
    const int tid  = threadIdx.x;
    const int b    = blockIdx.x & 7;          // XCD-pinned batch
    const int t0   = (blockIdx.x >> 3) * TBLK;
    const int lane = tid & 63;
    const int wv   = tid >> 6;                // wave id 0..7
    const int li   = lane & 15;
    const int gi   = lane >> 4;

    const float* encB = enc + (size_t)b * TE * DD;
    const float* decB = dec + (size_t)b * TD * DD;
    float*       outB = out + (size_t)b * TD * (2 * DD);

    // staging mapping: thread = (c4 = d-quad, rb = e-octet)
    const int c4 = tid & 127;
    const int rb = tid >> 7;

    // ---- Q stage (fp16 hi/lo) + dec passthrough to out[:, 0:512] ----
    for (int i = tid; i < TBLK * (DD / 4); i += 512) {
        int t   = i >> 7;     // 128 float4 per row
        int c4q = i & 127;
        float4 q = ((const float4*)(decB + (size_t)(t0 + t) * DD))[c4q];
        ((float4*)(outB + (size_t)(t0 + t) * (2 * DD)))[c4q] = q;
        f16 h0 = (f16)q.x, h1 = (f16)q.y, h2 = (f16)q.z, h3 = (f16)q.w;
        f16 l0 = (f16)(q.x - (float)h0), l1 = (f16)(q.y - (float)h1);
        f16 l2 = (f16)(q.z - (float)h2), l3 = (f16)(q.w - (float)h3);
        f16x4 hv = {h0, h1, h2, h3};
        f16x4 lv = {l0, l1, l2, l3};
        int off = swz1k(t, 8 * c4q);
        *(f16x4*)(sm + OQHI + off) = hv;
        *(f16x4*)(sm + OQLO + off) = lv;
    }

    // ---- K-chunk prefetch registers ----
    f32x4 st[8];

    // prologue: load + stage chunk 0
    {
        #pragma unroll
        for (int i = 0; i < 8; ++i)
            st[i] = *(const f32x4*)(encB + (size_t)(8 * rb + i) * DD + 4 * c4);
    }
    {
        f16 hv[8][4];
        #pragma unroll
        for (int i = 0; i < 8; ++i)
            #pragma unroll
            for (int k = 0; k < 4; ++k) hv[i][k] = (f16)st[i][k];
        #pragma unroll
        for (int i = 0; i < 8; ++i) {
            f16x4 h = {hv[i][0], hv[i][1], hv[i][2], hv[i][3]};
            *(f16x4*)(sm + OKHI + swz1k(8 * rb + i, 8 * c4)) = h;
        }
        #pragma unroll
        for (int k = 0; k < 4; ++k) {
            int d = 4 * c4 + k;
            char* rowp = sm + OKT + d * 80;
            int sig = ((d >> 3) & 3) << 4;
            f16x4 q0 = {hv[0][k], hv[1][k], hv[2][k], hv[3][k]};
            f16x4 q1 = {hv[4][k], hv[5][k], hv[6][k], hv[7][k]};
            *(f16x4*)(rowp + ((16 * rb + 0) ^ sig)) = q0;
            *(f16x4*)(rowp + ((16 * rb + 8) ^ sig)) = q1;
        }
    }
    __syncthreads();

    // softmax ownership: wave wv owns columns t = 4*wv + c, c = lane&3; er = lane>>2
    const int c    = lane & 3;
    const int er   = lane >> 2;
    const int tcol = 4 * wv + c;
    float mrun = -3.0e38f, lrun = 0.0f;
    const float L2E = 1.44269504088896f;

    // ctx^T accumulators: wave owns d in [64*wv, 64*wv+64): 4 d-tiles x 2 t-tiles
    f32x4 ctx[4][2];
    #pragma unroll
    for (int md = 0; md < 4; ++md) {
        ctx[md][0] = (f32x4){0.f, 0.f, 0.f, 0.f};
        ctx[md][1] = (f32x4){0.f, 0.f, 0.f, 0.f};
    }

    for (int ch = 0; ch < NCH; ++ch) {
        // ---- T14: issue next chunk's global loads (stay in flight through compute)
        if (ch + 1 < NCH) {
            const float* src = encB + (size_t)(ch + 1) * EBLK * DD;
            #pragma unroll
            for (int i = 0; i < 8; ++i)
                st[i] = *(const f32x4*)(src + (size_t)(8 * rb + i) * DD + 4 * c4);
        }

        // ---- QK^T partial: wave = k-slice [64*wv, 64*wv+64) over full 32x32 S ----
        f32x4 sacc[2][2];
        #pragma unroll
        for (int et = 0; et < 2; ++et) {
            sacc[et][0] = (f32x4){0.f, 0.f, 0.f, 0.f};
            sacc[et][1] = (f32x4){0.f, 0.f, 0.f, 0.f};
        }
        #pragma unroll
        for (int kk = 0; kk < 2; ++kk) {
            int d0 = 64 * wv + 32 * kk;
            int cb = 2 * d0 + 16 * gi;
            f16x8 aF[2], bH[2], bL[2];
            #pragma unroll
            for (int et = 0; et < 2; ++et)
                aF[et] = *(const f16x8*)(sm + OKHI + swz1k(16 * et + li, cb));
            #pragma unroll
            for (int tt = 0; tt < 2; ++tt) {
                bH[tt] = *(const f16x8*)(sm + OQHI + swz1k(16 * tt + li, cb));
                bL[tt] = *(const f16x8*)(sm + OQLO + swz1k(16 * tt + li, cb));
            }
            #pragma unroll
            for (int et = 0; et < 2; ++et)
                #pragma unroll
                for (int tt = 0; tt < 2; ++tt) {
                    sacc[et][tt] = __builtin_amdgcn_mfma_f32_16x16x32_f16(aF[et], bH[tt], sacc[et][tt], 0, 0, 0);
                    sacc[et][tt] = __builtin_amdgcn_mfma_f32_16x16x32_f16(aF[et], bL[tt], sacc[et][tt], 0, 0, 0);
                }
        }
        if (wv < 4) {
            #pragma unroll
            for (int et = 0; et < 2; ++et)
                #pragma unroll
                for (int tt = 0; tt < 2; ++tt)
                    #pragma unroll
                    for (int r = 0; r < 4; ++r) {
                        int erow = 16 * et + 4 * gi + r;
                        int tc   = 16 * tt + li;
                        *(float*)(sm + OS + wv * 4352 + erow * 136 + tc * 4) = sacc[et][tt][r];
                    }
        }
        __syncthreads();                              // B2
        if (wv >= 4) {
            #pragma unroll
            for (int et = 0; et < 2; ++et)
                #pragma unroll
                for (int tt = 0; tt < 2; ++tt)
                    #pragma unroll
                    for (int r = 0; r < 4; ++r) {
                        int erow = 16 * et + 4 * gi + r;
                        int tc   = 16 * tt + li;
                        float* p = (float*)(sm + OS + (wv - 4) * 4352 + erow * 136 + tc * 4);
                        *p += sacc[et][tt][r];
                    }
        }
        __syncthreads();                              // B3
        // ---- online softmax (owner waves; all lanes active) ----
        {
            float s1 = 0.f, s2 = 0.f;
            #pragma unroll
            for (int bu = 0; bu < 4; ++bu) {
                s1 += *(const float*)(sm + OS + bu * 4352 + er * 136 + tcol * 4);
                s2 += *(const float*)(sm + OS + bu * 4352 + (er + 16) * 136 + tcol * 4);
            }
            float v = fmaxf(s1, s2);
            v = fmaxf(v, __shfl_xor(v, 4));
            v = fmaxf(v, __shfl_xor(v, 8));
            v = fmaxf(v, __shfl_xor(v, 16));
            v = fmaxf(v, __shfl_xor(v, 32));
            float mnew  = fmaxf(mrun, v);
            float alpha = exp2f((mrun - mnew) * L2E);
            float p1 = exp2f((s1 - mnew) * L2E);
            float p2 = exp2f((s2 - mnew) * L2E);
            float ps = p1 + p2;
            ps += __shfl_xor(ps, 4);
            ps += __shfl_xor(ps, 8);
            ps += __shfl_xor(ps, 16);
            ps += __shfl_xor(ps, 32);
            lrun = lrun * alpha + ps;
            mrun = mnew;
            *(f16*)(sm + OP + tcol * 80 + 2 * er)        = (f16)p1;
            *(f16*)(sm + OP + tcol * 80 + 2 * (er + 16)) = (f16)p2;
            if (er == 0) *(float*)(sm + OAL + 4 * tcol) = alpha;
        }
        __syncthreads();                              // B4
        // ---- PV: ctx^T[d][t] += sum_e Kt[d][e] * P[t][e] ----
        {
            float a0 = *(const float*)(sm + OAL + 4 * li);
            float a1 = *(const float*)(sm + OAL + 4 * (16 + li));
            f16x8 bP0 = *(const f16x8*)(sm + OP + li * 80 + 16 * gi);
            f16x8 bP1 = *(const f16x8*)(sm + OP + (16 + li) * 80 + 16 * gi);
            #pragma unroll
            for (int md = 0; md < 4; ++md) {
                int dv = 64 * wv + 16 * md + li;
                int sig = ((dv >> 3) & 3) << 4;
                f16x8 aV = *(const f16x8*)(sm + OKT + dv * 80 + ((16 * gi) ^ sig));
                #pragma unroll
                for (int r = 0; r < 4; ++r) { ctx[md][0][r] *= a0; ctx[md][1][r] *= a1; }
                ctx[md][0] = __builtin_amdgcn_mfma_f32_16x16x32_f16(aV, bP0, ctx[md][0], 0, 0, 0);
                ctx[md][1] = __builtin_amdgcn_mfma_f32_16x16x32_f16(aV, bP1, ctx[md][1], 0, 0, 0);
            }
        }
        // ---- stage next chunk into LDS (loads already in flight) ----
        if (ch + 1 < NCH) {
            __syncthreads();                          // B0: all KT/Khi reads done
            f16 hv[8][4];
            #pragma unroll
            for (int i = 0; i < 8; ++i)
                #pragma unroll
                for (int k = 0; k < 4; ++k) hv[i][k] = (f16)st[i][k];
            #pragma unroll
            for (int i = 0; i < 8; ++i) {
                f16x4 h = {hv[i][0], hv[i][1], hv[i][2], hv[i][3]};
                *(f16x4*)(sm + OKHI + swz1k(8 * rb + i, 8 * c4)) = h;
            }
            #pragma unroll
            for (int k = 0; k < 4; ++k) {
                int d = 4 * c4 + k;
                char* rowp = sm + OKT + d * 80;
                int sig = ((d >> 3) & 3) << 4;
                f16x4 q0 = {hv[0][k], hv[1][k], hv[2][k], hv[3][k]};
                f16x4 q1 = {hv[4][k], hv[5][k], hv[6][k], hv[7][k]};
                *(f16x4*)(rowp + ((16 * rb + 0) ^ sig)) = q0;
                *(f16x4*)(rowp + ((16 * rb + 8) ^ sig)) = q1;
            }
            __syncthreads();                          // Bs: staged
        }
    }

    // ---- epilogue: divide by l, write context half ----
    if (er == 0) *(float*)(sm + OLL + 4 * tcol) = lrun;
    __syncthreads();
    float inv0 = 1.0f / *(const float*)(sm + OLL + 4 * li);
    float inv1 = 1.0f / *(const float*)(sm + OLL + 4 * (16 + li));
    #pragma unroll
    for (int md = 0; md < 4; ++md) {
        #pragma unroll
        for (int tt = 0; tt < 2; ++tt) {
            float inv = tt ? inv1 : inv0;
            int t = t0 + 16 * tt + li;
            int d = 64 * wv + 16 * md + 4 * gi;
            float4 o;
            o.x = ctx[md][tt][0] * inv;
            o.y = ctx[md][tt][1] * inv;
            o.z = ctx[md][tt][2] * inv;
            o.w = ctx[md][tt][3] * inv;
            *(float4*)(outB + (size_t)t * (2 * DD) + DD + d) = o;
        }
    }
}

extern "C" void kernel_launch(void* const* d_in, const int* in_sizes, int n_in,
                              void* d_out, int out_size, void* d_ws, size_t ws_size,
                              hipStream_t stream) {
    const float* enc = (const float*)d_in[0];
    const float* dec = (const float*)d_in[1];
    float* out = (float*)d_out;
    dim3 grid(NB * (TD / TBLK));   // 512 blocks: b = bid&7 (XCD pin), ttile = bid>>3
    dim3 block(512);
    attn_fused<<<grid, block, 0, stream>>>(enc, dec, out);
}

// Round 3
// 288.904 us; speedup vs baseline: 1.3188x; 1.0519x over previous
//
#include <hip/hip_runtime.h>

// Fused cross-attention: out = concat(dec, softmax_e(enc·dec^T)^T-weighted enc)
// B=8, T_enc=T_dec=2048, D=512, fp32 in/out.
// Flash-style: block = (batch, 32 decoder rows), encoder chunks of 32.
// QK^T split-fp16 (S = Khi*(Qhi+Qlo), fp32 MFMA accum).
// R3: Q-frags hoisted to regs (loop-invariant), Q-LDS reused as 8-way S partials
//     (no RMW round, 4 barriers/chunk), KT staging writes b128 (conflict fix),
//     prefetch depth 2, setprio around MFMA.

typedef _Float16 f16;
typedef f16 f16x8 __attribute__((ext_vector_type(8)));
typedef f16 f16x4 __attribute__((ext_vector_type(4)));
typedef float f32x4 __attribute__((ext_vector_type(4)));

#define NB 8
#define TE 2048
#define TD 2048
#define DD 512
#define TBLK 32
#define EBLK 32
#define NCH (TE / EBLK)

// LDS layout (bytes)
// Region A [0,65536): prologue Q staging; then S8/P/AL/LL
#define OQHI 0          // [32][512] f16, 1024B swizzled rows (prologue only)
#define OQLO 32768      // (prologue only)
#define OS8  0          // [8 bu][32 tc][36 erow] f32 (tc-major; 36 = pad)
#define OP   36864      // [32][40] f16  P[t][e]
#define OAL  39424      // [32] f32 alpha
#define OLL  39552      // [32] f32 l
// Region B: K buffers
#define OKHI 65536      // [32][512] f16, swizzled rows (QK A-operand)
#define OKT  98304      // [512][40] f16, 80B rows, sig-swizzled 16B slots (PV A-operand)
#define SMEM_BYTES 139264

__device__ __forceinline__ int swz1k(int row, int byteInRow) {
    return row * 1024 + (byteInRow ^ ((row & 7) << 4));
}

__global__ __launch_bounds__(512)
void attn_fused(const float* __restrict__ enc, const float* __restrict__ dec,
                float* __restrict__ out) {
    __shared__ __align__(16) char sm[SMEM_BYTES];
    const int tid  = threadIdx.x;
    const int b    = blockIdx.x & 7;          // XCD-pinned batch
    const int t0   = (blockIdx.x >> 3) * TBLK;
    const int lane = tid & 63;
    const int wv   = tid >> 6;
    const int li   = lane & 15;
    const int gi   = lane >> 4;

    const float* encB = enc + (size_t)b * TE * DD;
    const float* decB = dec + (size_t)b * TD * DD;
    float*       outB = out + (size_t)b * TD * (2 * DD);

    // staging mapping: thread = (c4 = d-quad, rb = e-octet)
    const int c4 = tid & 127;
    const int rb = tid >> 7;

    // ---- issue K0 loads early ----
    f32x4 st[8];
    #pragma unroll
    for (int i = 0; i < 8; ++i)
        st[i] = *(const f32x4*)(encB + (size_t)(8 * rb + i) * DD + 4 * c4);

    // ---- Q stage (fp16 hi/lo) + dec passthrough ----
    for (int i = tid; i < TBLK * (DD / 4); i += 512) {
        int t   = i >> 7;
        int c4q = i & 127;
        float4 q = ((const float4*)(decB + (size_t)(t0 + t) * DD))[c4q];
        ((float4*)(outB + (size_t)(t0 + t) * (2 * DD)))[c4q] = q;
        f16 h0 = (f16)q.x, h1 = (f16)q.y, h2 = (f16)q.z, h3 = (f16)q.w;
        f16 l0 = (f16)(q.x - (float)h0), l1 = (f16)(q.y - (float)h1);
        f16 l2 = (f16)(q.z - (float)h2), l3 = (f16)(q.w - (float)h3);
        f16x4 hv4 = {h0, h1, h2, h3};
        f16x4 lv4 = {l0, l1, l2, l3};
        int off = swz1k(t, 8 * c4q);
        *(f16x4*)(sm + OQHI + off) = hv4;
        *(f16x4*)(sm + OQLO + off) = lv4;
    }
    __syncthreads();

    // ---- hoist Q fragments to registers (loop-invariant) ----
    f16x8 qH[2][2], qL[2][2];
    #pragma unroll
    for (int kk = 0; kk < 2; ++kk) {
        int cb = 2 * (64 * wv + 32 * kk) + 16 * gi;
        #pragma unroll
        for (int tt = 0; tt < 2; ++tt) {
            qH[kk][tt] = *(const f16x8*)(sm + OQHI + swz1k(16 * tt + li, cb));
            qL[kk][tt] = *(const f16x8*)(sm + OQLO + swz1k(16 * tt + li, cb));
        }
    }
    __syncthreads();   // region A free for S8 from here

    // ---- stage K0 (Khi + KT), then issue K1 loads ----
    {
        f16 hv[8][4];
        #pragma unroll
        for (int i = 0; i < 8; ++i)
            #pragma unroll
            for (int k = 0; k < 4; ++k) hv[i][k] = (f16)st[i][k];
        #pragma unroll
        for (int i = 0; i < 8; ++i) {
            f16x4 h = {hv[i][0], hv[i][1], hv[i][2], hv[i][3]};
            *(f16x4*)(sm + OKHI + swz1k(8 * rb + i, 8 * c4)) = h;
        }
        #pragma unroll
        for (int k = 0; k < 4; ++k) {
            int d = 4 * c4 + k;
            int sig = ((d >> 3) & 3) << 4;
            f16x8 q8 = {hv[0][k], hv[1][k], hv[2][k], hv[3][k],
                        hv[4][k], hv[5][k], hv[6][k], hv[7][k]};
            *(f16x8*)(sm + OKT + d * 80 + ((16 * rb) ^ sig)) = q8;
        }
    }
    #pragma unroll
    for (int i = 0; i < 8; ++i)
        st[i] = *(const f32x4*)(encB + (size_t)(EBLK + 8 * rb + i) * DD + 4 * c4);
    __syncthreads();   // K0 staged

    // softmax ownership: wave wv owns t-cols 4*wv + c
    const int c    = lane & 3;
    const int er   = lane >> 2;
    const int tcol = 4 * wv + c;
    float mrun = -3.0e38f, lrun = 0.0f;
    const float L2E = 1.44269504088896f;

    f32x4 ctx[4][2];
    #pragma unroll
    for (int md = 0; md < 4; ++md) {
        ctx[md][0] = (f32x4){0.f, 0.f, 0.f, 0.f};
        ctx[md][1] = (f32x4){0.f, 0.f, 0.f, 0.f};
    }

    for (int ch = 0; ch < NCH; ++ch) {
        const bool more = (ch + 1 < NCH);
        // ---- QK^T: wave = k-slice [64wv, 64wv+64), full 32x32 S ----
        f32x4 sacc[2][2];
        #pragma unroll
        for (int et = 0; et < 2; ++et) {
            sacc[et][0] = (f32x4){0.f, 0.f, 0.f, 0.f};
            sacc[et][1] = (f32x4){0.f, 0.f, 0.f, 0.f};
        }
        __builtin_amdgcn_s_setprio(1);
        #pragma unroll
        for (int kk = 0; kk < 2; ++kk) {
            int cb = 2 * (64 * wv + 32 * kk) + 16 * gi;
            f16x8 aF[2];
            #pragma unroll
            for (int et = 0; et < 2; ++et)
                aF[et] = *(const f16x8*)(sm + OKHI + swz1k(16 * et + li, cb));
            #pragma unroll
            for (int et = 0; et < 2; ++et)
                #pragma unroll
                for (int tt = 0; tt < 2; ++tt) {
                    sacc[et][tt] = __builtin_amdgcn_mfma_f32_16x16x32_f16(aF[et], qH[kk][tt], sacc[et][tt], 0, 0, 0);
                    sacc[et][tt] = __builtin_amdgcn_mfma_f32_16x16x32_f16(aF[et], qL[kk][tt], sacc[et][tt], 0, 0, 0);
                }
        }
        __builtin_amdgcn_s_setprio(0);
        // ---- write S partials: buffer wv, tc-major, b128 per (et,tt) ----
        #pragma unroll
        for (int et = 0; et < 2; ++et)
            #pragma unroll
            for (int tt = 0; tt < 2; ++tt)
                *(f32x4*)(sm + OS8 + wv * 4608 + (16 * tt + li) * 144 + (16 * et + 4 * gi) * 4) = sacc[et][tt];
        __syncthreads();                              // B1
        // ---- online softmax (each wave owns 4 t-cols; all lanes active) ----
        f16 hv[8][4];
        {
            float s1 = 0.f, s2 = 0.f;
            #pragma unroll
            for (int bu = 0; bu < 8; ++bu) {
                s1 += *(const float*)(sm + OS8 + bu * 4608 + tcol * 144 + er * 4);
                s2 += *(const float*)(sm + OS8 + bu * 4608 + tcol * 144 + (er + 16) * 4);
            }
            float v = fmaxf(s1, s2);
            v = fmaxf(v, __shfl_xor(v, 4));
            v = fmaxf(v, __shfl_xor(v, 8));
            v = fmaxf(v, __shfl_xor(v, 16));
            v = fmaxf(v, __shfl_xor(v, 32));
            float mnew  = fmaxf(mrun, v);
            float alpha = exp2f((mrun - mnew) * L2E);
            float p1 = exp2f((s1 - mnew) * L2E);
            float p2 = exp2f((s2 - mnew) * L2E);
            float ps = p1 + p2;
            ps += __shfl_xor(ps, 4);
            ps += __shfl_xor(ps, 8);
            ps += __shfl_xor(ps, 16);
            ps += __shfl_xor(ps, 32);
            lrun = lrun * alpha + ps;
            mrun = mnew;
            *(f16*)(sm + OP + tcol * 80 + 2 * er)        = (f16)p1;
            *(f16*)(sm + OP + tcol * 80 + 2 * (er + 16)) = (f16)p2;
            if (er == 0) *(float*)(sm + OAL + 4 * tcol) = alpha;
        }
        // ---- overlap: cvt + Khi-write for ch+1 (Khi reads ended pre-B1) ----
        if (more) {
            #pragma unroll
            for (int i = 0; i < 8; ++i)
                #pragma unroll
                for (int k = 0; k < 4; ++k) hv[i][k] = (f16)st[i][k];
            #pragma unroll
            for (int i = 0; i < 8; ++i) {
                f16x4 h = {hv[i][0], hv[i][1], hv[i][2], hv[i][3]};
                *(f16x4*)(sm + OKHI + swz1k(8 * rb + i, 8 * c4)) = h;
            }
        }
        // ---- issue loads for ch+2 (in flight across PV + next QK) ----
        if (ch + 2 < NCH) {
            const float* src = encB + (size_t)(ch + 2) * EBLK * DD;
            #pragma unroll
            for (int i = 0; i < 8; ++i)
                st[i] = *(const f32x4*)(src + (size_t)(8 * rb + i) * DD + 4 * c4);
        }
        __syncthreads();                              // B2: P/AL ready
        // ---- PV: ctx^T[d][t] += sum_e KT[d][e] * P[t][e] ----
        {
            float a0 = *(const float*)(sm + OAL + 4 * li);
            float a1 = *(const float*)(sm + OAL + 4 * (16 + li));
            f16x8 bP0 = *(const f16x8*)(sm + OP + li * 80 + 16 * gi);
            f16x8 bP1 = *(const f16x8*)(sm + OP + (16 + li) * 80 + 16 * gi);
            __builtin_amdgcn_s_setprio(1);
            #pragma unroll
            for (int md = 0; md < 4; ++md) {
                int dv = 64 * wv + 16 * md + li;
                int sig = ((dv >> 3) & 3) << 4;
                f16x8 aV = *(const f16x8*)(sm + OKT + dv * 80 + ((16 * gi) ^ sig));
                #pragma unroll
                for (int r = 0; r < 4; ++r) { ctx[md][0][r] *= a0; ctx[md][1][r] *= a1; }
                ctx[md][0] = __builtin_amdgcn_mfma_f32_16x16x32_f16(aV, bP0, ctx[md][0], 0, 0, 0);
                ctx[md][1] = __builtin_amdgcn_mfma_f32_16x16x32_f16(aV, bP1, ctx[md][1], 0, 0, 0);
            }
            __builtin_amdgcn_s_setprio(0);
        }
        __syncthreads();                              // B3: KT reads done
        // ---- KT-write for ch+1 (b128, sig-spread: ~conflict-free) ----
        if (more) {
            #pragma unroll
            for (int k = 0; k < 4; ++k) {
                int d = 4 * c4 + k;
                int sig = ((d >> 3) & 3) << 4;
                f16x8 q8 = {hv[0][k], hv[1][k], hv[2][k], hv[3][k],
                            hv[4][k], hv[5][k], hv[6][k], hv[7][k]};
                *(f16x8*)(sm + OKT + d * 80 + ((16 * rb) ^ sig)) = q8;
            }
        }
        __syncthreads();                              // B4: staging visible
    }

    // ---- epilogue ----
    if (er == 0) *(float*)(sm + OLL + 4 * tcol) = lrun;
    __syncthreads();
    float inv0 = 1.0f / *(const float*)(sm + OLL + 4 * li);
    float inv1 = 1.0f / *(const float*)(sm + OLL + 4 * (16 + li));
    #pragma unroll
    for (int md = 0; md < 4; ++md) {
        #pragma unroll
        for (int tt = 0; tt < 2; ++tt) {
            float inv = tt ? inv1 : inv0;
            int t = t0 + 16 * tt + li;
            int d = 64 * wv + 16 * md + 4 * gi;
            float4 o;
            o.x = ctx[md][tt][0] * inv;
            o.y = ctx[md][tt][1] * inv;
            o.z = ctx[md][tt][2] * inv;
            o.w = ctx[md][tt][3] * inv;
            *(float4*)(outB + (size_t)t * (2 * DD) + DD + d) = o;
        }
    }
}

extern "C" void kernel_launch(void* const* d_in, const int* in_sizes, int n_in,
                              void* d_out, int out_size, void* d_ws, size_t ws_size,
                              hipStream_t stream) {
    const float* enc = (const float*)d_in[0];
    const float* dec = (const float*)d_in[1];
    float* out = (float*)d_out;
    dim3 grid(NB * (TD / TBLK));
    dim3 block(512);
    attn_fused<<<grid, block, 0, stream>>>(enc, dec, out);
}

// Round 5
// 171.384 us; speedup vs baseline: 2.2232x; 1.6857x over previous
//
#include <hip/hip_runtime.h>

// Fused cross-attention: out = concat(dec, softmax_e(enc·dec^T)^T-weighted enc)
// B=8, T_enc=T_dec=2048, D=512, fp32 in/out.
// R5: fixes R4's LDS overflow (KT buffer is 40960 B, was sized 20480).
// TBLK=64 (256 blocks, 1/CU), Q hi/lo frags in registers, 2-barrier pipeline:
// phase A = QK(ch); phase B = softmax(ch) ∥ PV(ch-1) ∥ Khi-stage(ch+1) ∥ loads(ch+2);
// phase C = KT-write(ch) from held registers (single KT buffer, one-iter-behind).
// T13 defer-max (THR=8) with block-uniform rescale gating.

typedef _Float16 f16;
typedef f16 f16x8 __attribute__((ext_vector_type(8)));
typedef f16 f16x4 __attribute__((ext_vector_type(4)));
typedef float f32x4 __attribute__((ext_vector_type(4)));

#define NB 8
#define TE 2048
#define TD 2048
#define DD 512
#define TBLK 64
#define EBLK 32
#define NCH (TE / EBLK)

// LDS layout (bytes) — audited: no region overlaps
#define OKHI 0          // [32][512] f16 = 32768B, 1024B swizzled rows (QK A-operand)
#define OKT  32768      // [512][40] f16 = 40960B, 80B rows, sig-swizzled (PV A-operand, SINGLE buffer)
#define OS8  73728      // 8 bu x [64 tc][36 er] f32 = 73728B (tc-major partial S)
#define OP   147456     // 2 x [64][40] f16 = 2x5120B P[t][e]
#define OPSZ 5120
#define OAL  157696     // 2 x 64 f32 alpha
#define OLL  158208     // 64 f32 l
#define OFLG 158464     // 2 x 8 u32 rescale flags
#define SMEM_BYTES 158528

__device__ __forceinline__ int swz1k(int row, int byteInRow) {
    return row * 1024 + (byteInRow ^ ((row & 7) << 4));
}

__global__ __launch_bounds__(512, 2)
void attn_fused(const float* __restrict__ enc, const float* __restrict__ dec,
                float* __restrict__ out) {
    __shared__ __align__(16) char sm[SMEM_BYTES];
    const int tid  = threadIdx.x;
    const int b    = blockIdx.x & 7;          // XCD-pinned batch
    const int t0   = (blockIdx.x >> 3) * TBLK;
    const int lane = tid & 63;
    const int wv   = tid >> 6;
    const int li   = lane & 15;
    const int gi   = lane >> 4;
    const float L2E = 1.44269504088896f;

    const float* encB = enc + (size_t)b * TE * DD;
    const float* decB = dec + (size_t)b * TD * DD;
    float*       outB = out + (size_t)b * TD * (2 * DD);

    // staging mapping: thread = (c4 = d-quad, rb = e-octet)
    const int c4 = tid & 127;
    const int rb = tid >> 7;

    // ---- issue K0 loads ----
    f32x4 st[8];
    #pragma unroll
    for (int i = 0; i < 8; ++i)
        st[i] = *(const f32x4*)(encB + (size_t)(8 * rb + i) * DD + 4 * c4);

    // ---- Q fragments (hi/lo) direct from global into registers ----
    f16x8 qH[2][4], qL[2][4];
    #pragma unroll
    for (int kk = 0; kk < 2; ++kk)
        #pragma unroll
        for (int tt = 0; tt < 4; ++tt) {
            const float* qp = decB + (size_t)(t0 + 16 * tt + li) * DD + 64 * wv + 32 * kk + 8 * gi;
            f32x4 q0 = *(const f32x4*)qp;
            f32x4 q1 = *(const f32x4*)(qp + 4);
            f16x8 h, l;
            #pragma unroll
            for (int j = 0; j < 4; ++j) {
                f16 h0 = (f16)q0[j]; h[j]     = h0; l[j]     = (f16)(q0[j] - (float)h0);
                f16 h1 = (f16)q1[j]; h[4 + j] = h1; l[4 + j] = (f16)(q1[j] - (float)h1);
            }
            qH[kk][tt] = h; qL[kk][tt] = l;
        }

    // ---- cvt K0 into hvB + Khi-write(0); KT(0) is written in iter 0 phase C ----
    f16x4 hvB[8];
    #pragma unroll
    for (int i = 0; i < 8; ++i) {
        f16x4 h4 = {(f16)st[i][0], (f16)st[i][1], (f16)st[i][2], (f16)st[i][3]};
        hvB[i] = h4;
        *(f16x4*)(sm + OKHI + swz1k(8 * rb + i, 8 * c4)) = h4;
    }
    // issue K1 loads
    #pragma unroll
    for (int i = 0; i < 8; ++i)
        st[i] = *(const f32x4*)(encB + (size_t)(EBLK + 8 * rb + i) * DD + 4 * c4);
    __syncthreads();

    // softmax ownership: wave wv owns t-cols [8wv, 8wv+8); 8 lanes per col
    const int cq   = lane & 7;
    const int erq  = lane >> 3;
    const int tcol = 8 * wv + cq;
    float mrun = -1.0e30f, lrun = 0.0f;

    f32x4 ctx[4][4];
    #pragma unroll
    for (int md = 0; md < 4; ++md)
        #pragma unroll
        for (int tt = 0; tt < 4; ++tt)
            ctx[md][tt] = (f32x4){0.f, 0.f, 0.f, 0.f};

    for (int ch = 0; ch < NCH; ++ch) {
        const int pb = ch & 1;       // P/OAL/FLG write side for chunk ch
        const int qb = pb ^ 1;       // side of chunk ch-1 (PV reads)
        const bool doPV = (ch > 0);
        const bool more = (ch + 1 < NCH);

        // ---- phase A: QK(ch), S8 partial writes ----
        f32x4 sacc[2][4];
        #pragma unroll
        for (int et = 0; et < 2; ++et)
            #pragma unroll
            for (int tt = 0; tt < 4; ++tt)
                sacc[et][tt] = (f32x4){0.f, 0.f, 0.f, 0.f};
        __builtin_amdgcn_s_setprio(1);
        #pragma unroll
        for (int kk = 0; kk < 2; ++kk) {
            int cb = 2 * (64 * wv + 32 * kk) + 16 * gi;
            f16x8 aF[2];
            #pragma unroll
            for (int et = 0; et < 2; ++et)
                aF[et] = *(const f16x8*)(sm + OKHI + swz1k(16 * et + li, cb));
            #pragma unroll
            for (int et = 0; et < 2; ++et)
                #pragma unroll
                for (int tt = 0; tt < 4; ++tt) {
                    sacc[et][tt] = __builtin_amdgcn_mfma_f32_16x16x32_f16(aF[et], qH[kk][tt], sacc[et][tt], 0, 0, 0);
                    sacc[et][tt] = __builtin_amdgcn_mfma_f32_16x16x32_f16(aF[et], qL[kk][tt], sacc[et][tt], 0, 0, 0);
                }
        }
        __builtin_amdgcn_s_setprio(0);
        #pragma unroll
        for (int et = 0; et < 2; ++et)
            #pragma unroll
            for (int tt = 0; tt < 4; ++tt)
                *(f32x4*)(sm + OS8 + wv * 9216 + (16 * tt + li) * 144 + 64 * et + 16 * gi) = sacc[et][tt];
        __syncthreads();                                   // B1

        // ---- phase B: softmax(ch) ∥ PV(ch-1) ∥ stage Khi(ch+1) ∥ loads(ch+2) ----
        bool doR = false;
        f16x8 bP[4];
        if (doPV) {
            const uint4* fp = (const uint4*)(sm + OFLG + 32 * qb);
            uint4 f0 = fp[0], f1 = fp[1];
            doR = (f0.x | f0.y | f0.z | f0.w | f1.x | f1.y | f1.z | f1.w) != 0;
            #pragma unroll
            for (int tt = 0; tt < 4; ++tt)
                bP[tt] = *(const f16x8*)(sm + OP + OPSZ * qb + (16 * tt + li) * 80 + 16 * gi);
        }
        // softmax(ch)
        {
            f32x4 s4 = (f32x4){0.f, 0.f, 0.f, 0.f};
            #pragma unroll
            for (int bu = 0; bu < 8; ++bu)
                s4 += *(const f32x4*)(sm + OS8 + bu * 9216 + tcol * 144 + 16 * erq);
            float pm = fmaxf(fmaxf(s4[0], s4[1]), fmaxf(s4[2], s4[3]));
            pm = fmaxf(pm, __shfl_xor(pm, 8));
            pm = fmaxf(pm, __shfl_xor(pm, 16));
            pm = fmaxf(pm, __shfl_xor(pm, 32));
            bool needc = pm > mrun + 8.0f;                 // T13 defer-max, THR=8
            unsigned long long bal = __ballot(needc);
            if (lane == 0) *(unsigned*)(sm + OFLG + 32 * pb + 4 * wv) = (bal != 0ULL) ? 1u : 0u;
            float mnew  = needc ? pm : mrun;
            float alpha = needc ? exp2f((mrun - mnew) * L2E) : 1.0f;
            f32x4 p4;
            #pragma unroll
            for (int j = 0; j < 4; ++j) p4[j] = exp2f((s4[j] - mnew) * L2E);
            float ps = p4[0] + p4[1] + p4[2] + p4[3];
            ps += __shfl_xor(ps, 8);
            ps += __shfl_xor(ps, 16);
            ps += __shfl_xor(ps, 32);
            lrun = lrun * alpha + ps;
            mrun = mnew;
            f16x4 pw = {(f16)p4[0], (f16)p4[1], (f16)p4[2], (f16)p4[3]};
            *(f16x4*)(sm + OP + OPSZ * pb + tcol * 80 + 8 * erq) = pw;
            if (erq == 0) *(float*)(sm + OAL + 256 * pb + 4 * tcol) = alpha;
        }
        // PV(ch-1) — KT currently holds chunk ch-1 (written in phase C of iter ch-1)
        if (doPV) {
            if (doR) {
                float av[4];
                #pragma unroll
                for (int tt = 0; tt < 4; ++tt)
                    av[tt] = *(const float*)(sm + OAL + 256 * qb + 4 * (16 * tt + li));
                #pragma unroll
                for (int md = 0; md < 4; ++md)
                    #pragma unroll
                    for (int tt = 0; tt < 4; ++tt)
                        #pragma unroll
                        for (int r = 0; r < 4; ++r) ctx[md][tt][r] *= av[tt];
            }
            __builtin_amdgcn_s_setprio(1);
            #pragma unroll
            for (int md = 0; md < 4; ++md) {
                int dv = 64 * wv + 16 * md + li;
                int sig = ((dv >> 3) & 3) << 4;
                f16x8 a = *(const f16x8*)(sm + OKT + dv * 80 + ((16 * gi) ^ sig));
                #pragma unroll
                for (int tt = 0; tt < 4; ++tt)
                    ctx[md][tt] = __builtin_amdgcn_mfma_f32_16x16x32_f16(a, bP[tt], ctx[md][tt], 0, 0, 0);
            }
            __builtin_amdgcn_s_setprio(0);
        }
        // cvt st(ch+1) -> hvA + Khi-write(ch+1); issue loads(ch+2)
        f16x4 hvA[8];
        if (more) {
            #pragma unroll
            for (int i = 0; i < 8; ++i) {
                f16x4 h4 = {(f16)st[i][0], (f16)st[i][1], (f16)st[i][2], (f16)st[i][3]};
                hvA[i] = h4;
                *(f16x4*)(sm + OKHI + swz1k(8 * rb + i, 8 * c4)) = h4;
            }
            if (ch + 2 < NCH) {
                const float* src = encB + (size_t)(ch + 2) * EBLK * DD;
                #pragma unroll
                for (int i = 0; i < 8; ++i)
                    st[i] = *(const f32x4*)(src + (size_t)(8 * rb + i) * DD + 4 * c4);
            }
        }
        __syncthreads();                                   // B2
        // ---- phase C: KT-write(ch) from hvB (PV(ch-1) reads finished at B2;
        //      next read, PV(ch) in iter ch+1, is after B1 of iter ch+1) ----
        #pragma unroll
        for (int k = 0; k < 4; ++k) {
            int d = 4 * c4 + k;
            int sig = ((d >> 3) & 3) << 4;
            f16x8 q8 = {hvB[0][k], hvB[1][k], hvB[2][k], hvB[3][k],
                        hvB[4][k], hvB[5][k], hvB[6][k], hvB[7][k]};
            *(f16x8*)(sm + OKT + d * 80 + ((16 * rb) ^ sig)) = q8;
        }
        if (more) {
            #pragma unroll
            for (int i = 0; i < 8; ++i) hvB[i] = hvA[i];
        }
    }

    __syncthreads();   // KT(NCH-1) written in last phase C — make visible

    // ---- final PV(NCH-1) ----
    {
        const int qb2 = (NCH - 1) & 1;
        const uint4* fp = (const uint4*)(sm + OFLG + 32 * qb2);
        uint4 f0 = fp[0], f1 = fp[1];
        bool doR = (f0.x | f0.y | f0.z | f0.w | f1.x | f1.y | f1.z | f1.w) != 0;
        f16x8 bP[4];
        #pragma unroll
        for (int tt = 0; tt < 4; ++tt)
            bP[tt] = *(const f16x8*)(sm + OP + OPSZ * qb2 + (16 * tt + li) * 80 + 16 * gi);
        if (doR) {
            float av[4];
            #pragma unroll
            for (int tt = 0; tt < 4; ++tt)
                av[tt] = *(const float*)(sm + OAL + 256 * qb2 + 4 * (16 * tt + li));
            #pragma unroll
            for (int md = 0; md < 4; ++md)
                #pragma unroll
                for (int tt = 0; tt < 4; ++tt)
                    #pragma unroll
                    for (int r = 0; r < 4; ++r) ctx[md][tt][r] *= av[tt];
        }
        #pragma unroll
        for (int md = 0; md < 4; ++md) {
            int dv = 64 * wv + 16 * md + li;
            int sig = ((dv >> 3) & 3) << 4;
            f16x8 a = *(const f16x8*)(sm + OKT + dv * 80 + ((16 * gi) ^ sig));
            #pragma unroll
            for (int tt = 0; tt < 4; ++tt)
                ctx[md][tt] = __builtin_amdgcn_mfma_f32_16x16x32_f16(a, bP[tt], ctx[md][tt], 0, 0, 0);
        }
    }

    // ---- epilogue: l-normalize + context writes + dec passthrough ----
    if (erq == 0) *(float*)(sm + OLL + 4 * tcol) = lrun;
    __syncthreads();
    float inv[4];
    #pragma unroll
    for (int tt = 0; tt < 4; ++tt)
        inv[tt] = 1.0f / *(const float*)(sm + OLL + 4 * (16 * tt + li));
    #pragma unroll
    for (int md = 0; md < 4; ++md)
        #pragma unroll
        for (int tt = 0; tt < 4; ++tt) {
            int t = t0 + 16 * tt + li;
            int d = 64 * wv + 16 * md + 4 * gi;
            float4 o;
            o.x = ctx[md][tt][0] * inv[tt];
            o.y = ctx[md][tt][1] * inv[tt];
            o.z = ctx[md][tt][2] * inv[tt];
            o.w = ctx[md][tt][3] * inv[tt];
            *(float4*)(outB + (size_t)t * (2 * DD) + DD + d) = o;
        }
    #pragma unroll
    for (int it = 0; it < TBLK * (DD / 4) / 512; ++it) {
        int i = tid + it * 512;
        int t = i >> 7, cc = i & 127;
        float4 q = ((const float4*)(decB + (size_t)(t0 + t) * DD))[cc];
        ((float4*)(outB + (size_t)(t0 + t) * (2 * DD)))[cc] = q;
    }
}

extern "C" void kernel_launch(void* const* d_in, const int* in_sizes, int n_in,
                              void* d_out, int out_size, void* d_ws, size_t ws_size,
                              hipStream_t stream) {
    const float* enc = (const float*)d_in[0];
    const float* dec = (const float*)d_in[1];
    float* out = (float*)d_out;
    dim3 grid(NB * (TD / TBLK));   // 256 blocks: b = bid&7 (XCD pin), ttile = bid>>3
    dim3 block(512);
    attn_fused<<<grid, block, 0, stream>>>(enc, dec, out);
}